// Round 9
// baseline (443.739 us; speedup 1.0000x reference)
//
#include <hip/hip_runtime.h>

#define NN   100000
#define EE   1600000
constexpr int RR = 8;
constexpr int BBASES = 4;
constexpr int SCAN_CHUNK = 1024;
constexpr int NBLK = (NN + SCAN_CHUNK - 1) / SCAN_CHUNK; // 98
constexpr int NBUK = 98;                                 // coarse buckets (dst>>10)
constexpr int EPB  = 4096;                               // edges per bin_pass1 block
constexpr int P1BLOCKS = (EE + EPB - 1) / EPB;           // 391

typedef __attribute__((ext_vector_type(8))) short short8;
typedef __attribute__((ext_vector_type(4))) float f32x4;

__device__ __forceinline__ unsigned pack2(float x, float y) {
    unsigned xu = __float_as_uint(x);
    unsigned yu = __float_as_uint(y);
    xu = (xu + 0x7fffu + ((xu >> 16) & 1u)) >> 16;
    yu = (yu + 0x7fffu + ((yu >> 16) & 1u)) & 0xffff0000u;
    return xu | yu;
}

__device__ __forceinline__ unsigned short bf16r(float x) {
    unsigned u = __float_as_uint(x);
    return (unsigned short)((u + 0x7fffu + ((u >> 16) & 1u)) >> 16);
}

// async global->LDS 16B: per-lane global src, wave-uniform LDS base (+lane*16 by HW)
__device__ __forceinline__ void async16(const void* g, void* l) {
    __builtin_amdgcn_global_load_lds(
        (const __attribute__((address_space(1))) void*)g,
        (__attribute__((address_space(3))) void*)l, 16, 0, 0);
}

// ---------------- CSR build: count + scan ----------------

__global__ __launch_bounds__(256) void count_kernel(const int* __restrict__ dst,
                                                    int* __restrict__ counts) {
    int e = blockIdx.x * 256 + threadIdx.x;
    if (e < EE) atomicAdd(&counts[dst[e]], 1);
}

__global__ __launch_bounds__(256) void scan1(const int* __restrict__ counts,
                                             int* __restrict__ offsets,
                                             int* __restrict__ totals) {
    __shared__ int lds[256];
    int b = blockIdx.x, tid = threadIdx.x;
    int base = b * SCAN_CHUNK + tid * 4;
    int v0 = (base + 0 < NN) ? counts[base + 0] : 0;
    int v1 = (base + 1 < NN) ? counts[base + 1] : 0;
    int v2 = (base + 2 < NN) ? counts[base + 2] : 0;
    int v3 = (base + 3 < NN) ? counts[base + 3] : 0;
    int s0 = v0, s1 = s0 + v1, s2 = s1 + v2, s3 = s2 + v3;
    lds[tid] = s3;
    __syncthreads();
    for (int d = 1; d < 256; d <<= 1) {
        int x = (tid >= d) ? lds[tid - d] : 0;
        __syncthreads();
        lds[tid] += x;
        __syncthreads();
    }
    int incl = lds[tid];
    int prefix = incl - s3;
    if (base + 0 < NN) offsets[base + 0] = prefix;
    if (base + 1 < NN) offsets[base + 1] = prefix + s0;
    if (base + 2 < NN) offsets[base + 2] = prefix + s1;
    if (base + 3 < NN) offsets[base + 3] = prefix + s2;
    if (tid == 255) totals[b] = lds[255];
}

// parallel chunk-total scan (128 thr) + gcursor init (replaces 1-thread scan2 + init_cursor)
__global__ __launch_bounds__(128) void scan2(int* __restrict__ totals,
                                             int* __restrict__ offsets,
                                             int* __restrict__ gcursor) {
    __shared__ int s[128];
    int tid = threadIdx.x;
    int v = (tid < NBLK) ? totals[tid] : 0;
    s[tid] = v;
    __syncthreads();
    for (int d = 1; d < 128; d <<= 1) {
        int x = (tid >= d) ? s[tid - d] : 0;
        __syncthreads();
        s[tid] += x;
        __syncthreads();
    }
    int excl = s[tid] - v;
    if (tid < NBLK) {
        totals[tid] = excl;
        gcursor[tid] = excl;      // bucket base == global offset of chunk's first node
    }
    if (tid == NBLK - 1) offsets[NN] = excl + v;   // == EE
}

__global__ __launch_bounds__(256) void scan3(int* __restrict__ offsets,
                                             const int* __restrict__ totals) {
    int i = blockIdx.x * 256 + threadIdx.x;
    if (i < NN) offsets[i] += totals[i >> 10];
}

// ---------------- edge binning ----------------

__global__ __launch_bounds__(256) void bin_pass1(const int* __restrict__ src,
                                                 const int* __restrict__ dst,
                                                 const int* __restrict__ et,
                                                 int* __restrict__ gcursor,
                                                 unsigned* __restrict__ tmp) {
    __shared__ unsigned stage[EPB];   // 16 KB
    __shared__ int hist[128];
    __shared__ int sc[128];
    __shared__ int lb[128];
    __shared__ int gb[128];
    int tid = threadIdx.x;
    long e0 = (long)blockIdx.x * EPB;
    if (tid < 128) hist[tid] = 0;
    __syncthreads();

    unsigned w[16];
    int bk[16], pos[16];
#pragma unroll
    for (int i = 0; i < 16; ++i) {
        long e = e0 + i * 256 + tid;
        bool valid = e < EE;
        int d = valid ? dst[e] : 0;
        int s = valid ? src[e] : 0;
        int r = valid ? et[e] : 0;
        bk[i] = d >> 10;
        w[i] = (unsigned)s | ((unsigned)r << 17) | ((unsigned)(d & 1023) << 20);
        pos[i] = valid ? atomicAdd(&hist[bk[i]], 1) : -1;
    }
    __syncthreads();
    if (tid < 128) sc[tid] = hist[tid];
    __syncthreads();
    for (int d = 1; d < 128; d <<= 1) {
        int v = 0;
        if (tid < 128 && tid >= d) v = sc[tid - d];
        __syncthreads();
        if (tid < 128) sc[tid] += v;
        __syncthreads();
    }
    if (tid < 128) lb[tid] = sc[tid] - hist[tid];
    if (tid < NBUK && hist[tid] > 0) gb[tid] = atomicAdd(&gcursor[tid], hist[tid]);
    __syncthreads();
    int total = sc[127];
#pragma unroll
    for (int i = 0; i < 16; ++i) {
        if (pos[i] >= 0) stage[lb[bk[i]] + pos[i]] = w[i];
    }
    __syncthreads();
    for (int s = tid; s < total; s += 256) {
        int lo = 0, hi = 127;
#pragma unroll
        for (int it = 0; it < 7; ++it) {
            int mid = (lo + hi + 1) >> 1;
            if (lb[mid] <= s) lo = mid; else hi = mid - 1;
        }
        tmp[gb[lo] + (s - lb[lo])] = stage[s];
    }
}

__global__ __launch_bounds__(1024) void bin_pass2(const unsigned* __restrict__ tmp,
                                                  const int* __restrict__ offsets,
                                                  int* __restrict__ packed) {
    __shared__ int cur[1024];
    __shared__ int offs[1025];
    int b = blockIdx.x, tid = threadIdx.x;
    int nb0 = b << 10;
    int nend = nb0 + 1024; if (nend > NN) nend = NN;
    int nloc = nend - nb0;
    cur[tid] = 0;
    for (int i = tid; i <= nloc; i += 1024) offs[i] = offsets[nb0 + i];
    __syncthreads();
    int beg = offs[0], end = offs[nloc];
    for (int e = beg + tid; e < end; e += 1024) {
        unsigned wv = tmp[e];
        int dl = (wv >> 20) & 1023;
        int p = offs[dl] + atomicAdd(&cur[dl], 1);
        packed[p] = (int)((wv & 0x1FFFFu) | (((wv >> 17) & 7u) << 20));
    }
}

// ---------------- weight conversions ----------------

__global__ __launch_bounds__(256) void convert_weights(const float* __restrict__ basis0,
                                                       const float* __restrict__ loop0,
                                                       const float* __restrict__ basis1,
                                                       const float* __restrict__ loop1,
                                                       const float* __restrict__ win,
                                                       const float* __restrict__ wout,
                                                       unsigned short* __restrict__ BT0,
                                                       unsigned short* __restrict__ BT1,
                                                       unsigned short* __restrict__ winT,
                                                       unsigned short* __restrict__ woutT) {
    int i = blockIdx.x * 256 + threadIdx.x;
    if (i < 81920) {
        int n = i / 640, k = i % 640;
        BT0[i] = bf16r(k < 512 ? basis0[(size_t)k * 128 + n] : loop0[(size_t)(k - 512) * 128 + n]);
    } else if (i < 163840) {
        int j = i - 81920;
        int n = j / 640, k = j % 640;
        BT1[j] = bf16r(k < 512 ? basis1[(size_t)k * 128 + n] : loop1[(size_t)(k - 512) * 128 + n]);
    } else if (i < 180224) {
        int j = i - 163840;
        int n = j >> 7, k = j & 127;
        winT[j] = bf16r(win[(size_t)k * 128 + n]);
    } else if (i < 188416) {
        int j = i - 180224;
        int n = j >> 7, k = j & 127;
        woutT[j] = bf16r(wout[(size_t)k * 64 + n]);
    }
}

// ---------------- generic MFMA GEMM, K=128 (in/out layers) ----------------
template <int NC, bool F32OUT, bool AF32>
__global__ __launch_bounds__(256) void gemm128(const void* __restrict__ Aptr,
                                               const unsigned short* __restrict__ BT,
                                               const float* __restrict__ bias,
                                               void* __restrict__ outp, int M) {
    constexpr int NFRAG = NC / 32;
    constexpr int BQ = NC * 8 / 256;
    __shared__ __align__(16) char As[2][16384];
    __shared__ __align__(16) char Bs[2][NC * 128];
    int tid = threadIdx.x;
    int lane = tid & 63;
    int wave = tid >> 6;
    int wm = wave >> 1, wn = wave & 1;
    int m0 = blockIdx.x * 128;

    uint4 areg[4], breg[BQ];
    auto loadA = [&](int c) {
#pragma unroll
        for (int q = 0; q < 4; ++q) {
            int lin = q * 256 + tid;
            int row = lin >> 3, slot = lin & 7;
            int gr = m0 + row;
            gr = (gr < M) ? gr : (M - 1);
            if (AF32) {
                const float* fp = (const float*)Aptr + (size_t)gr * 128 + c * 64 + slot * 8;
                float4 v0 = *(const float4*)fp;
                float4 v1 = *(const float4*)(fp + 4);
                areg[q].x = pack2(v0.x, v0.y);
                areg[q].y = pack2(v0.z, v0.w);
                areg[q].z = pack2(v1.x, v1.y);
                areg[q].w = pack2(v1.z, v1.w);
            } else {
                areg[q] = *(const uint4*)((const char*)Aptr + (size_t)gr * 256 + c * 128 + slot * 16);
            }
        }
    };
    auto loadB = [&](int c) {
#pragma unroll
        for (int q = 0; q < BQ; ++q) {
            int lin = q * 256 + tid;
            int n = lin >> 3, slot = lin & 7;
            breg[q] = *(const uint4*)((const char*)BT + (size_t)n * 256 + c * 128 + slot * 16);
        }
    };

    f32x4 acc[4][NFRAG];
#pragma unroll
    for (int m = 0; m < 4; ++m)
#pragma unroll
        for (int n = 0; n < NFRAG; ++n) acc[m][n] = (f32x4)0.f;

    loadA(0); loadB(0);
    int swz = (lane & 7) << 4;

    for (int c = 0; c < 2; ++c) {
        int buf = c & 1;
#pragma unroll
        for (int q = 0; q < 4; ++q) {
            int lin = q * 256 + tid;
            int row = lin >> 3, slot = lin & 7;
            *(uint4*)(As[buf] + row * 128 + ((slot * 16) ^ ((row & 7) << 4))) = areg[q];
        }
#pragma unroll
        for (int q = 0; q < BQ; ++q) {
            int lin = q * 256 + tid;
            int row = lin >> 3, slot = lin & 7;
            *(uint4*)(Bs[buf] + row * 128 + ((slot * 16) ^ ((row & 7) << 4))) = breg[q];
        }
        __syncthreads();
        if (c < 1) { loadA(1); loadB(1); }
#pragma unroll
        for (int ks = 0; ks < 2; ++ks) {
            short8 a[4], b[NFRAG];
            int kb = ks * 64 + (lane >> 4) * 16;
#pragma unroll
            for (int m = 0; m < 4; ++m) {
                int row = wm * 64 + m * 16 + (lane & 15);
                a[m] = *(const short8*)(As[buf] + row * 128 + (kb ^ swz));
            }
#pragma unroll
            for (int n = 0; n < NFRAG; ++n) {
                int col = wn * (NC / 2) + n * 16 + (lane & 15);
                b[n] = *(const short8*)(Bs[buf] + col * 128 + (kb ^ swz));
            }
#pragma unroll
            for (int m = 0; m < 4; ++m)
#pragma unroll
                for (int n = 0; n < NFRAG; ++n)
                    acc[m][n] = __builtin_amdgcn_mfma_f32_16x16x32_bf16(a[m], b[n], acc[m][n], 0, 0, 0);
        }
        __syncthreads();
    }

    int colbase = wn * (NC / 2) + (lane & 15);
    float bias_v[NFRAG];
#pragma unroll
    for (int n = 0; n < NFRAG; ++n) bias_v[n] = bias[colbase + n * 16];
#pragma unroll
    for (int m = 0; m < 4; ++m) {
        int rl0 = m0 + wm * 64 + m * 16 + ((lane >> 4) << 2);
#pragma unroll
        for (int n = 0; n < NFRAG; ++n) {
            int col = colbase + n * 16;
#pragma unroll
            for (int q = 0; q < 4; ++q) {
                float v = fmaxf(acc[m][n][q] + bias_v[n], 0.f);
                int row = rl0 + q;
                if (F32OUT) {
                    if (row < M) ((float*)outp)[(size_t)row * NC + col] = v;
                } else {
                    float vo = __shfl_xor(v, 1);
                    if (((lane & 1) == 0) && row < M)
                        ((unsigned*)outp)[(size_t)row * (NC / 2) + (col >> 1)] = pack2(v, vo);
                }
            }
        }
    }
}

// ---------------- aggregation (uint4 edge loads, 8-deep gather unroll) ----------------

__global__ __launch_bounds__(256) void agg_kernel(const unsigned* __restrict__ hin, // [N][64] bf16x2
                                                  const int* __restrict__ offsets,
                                                  const int* __restrict__ packed,
                                                  const float* __restrict__ wcomp,  // [8][4]
                                                  unsigned* __restrict__ tbuf,      // [len][256]
                                                  int chunk_start, int chunk_len) {
    __shared__ float wc[32];
    int tid = threadIdx.x;
    if (tid < 32) wc[tid] = wcomp[tid];
    __syncthreads();
    int nl = blockIdx.x * 4 + (tid >> 6);
    int lane = tid & 63;
    if (nl >= chunk_len) return;
    int n = chunk_start + nl;
    int beg = offsets[n], end = offsets[n + 1];
    float a0x = 0.f, a0y = 0.f, a1x = 0.f, a1y = 0.f;
    float a2x = 0.f, a2y = 0.f, a3x = 0.f, a3y = 0.f;
    auto edge = [&](unsigned u, unsigned hv) {
        int r = (int)(u >> 20);
        float hx = __uint_as_float(hv << 16);
        float hy = __uint_as_float(hv & 0xffff0000u);
        float w0 = wc[r * 4 + 0], w1 = wc[r * 4 + 1];
        float w2 = wc[r * 4 + 2], w3 = wc[r * 4 + 3];
        a0x = fmaf(w0, hx, a0x); a0y = fmaf(w0, hy, a0y);
        a1x = fmaf(w1, hx, a1x); a1y = fmaf(w1, hy, a1y);
        a2x = fmaf(w2, hx, a2x); a2y = fmaf(w2, hy, a2y);
        a3x = fmaf(w3, hx, a3x); a3y = fmaf(w3, hy, a3y);
    };
    int e = beg;
    // head: scalar until e is 4-aligned (uint4 load alignment)
    int ehead = (beg + 3) & ~3;
    if (ehead > end) ehead = end;
    for (; e < ehead; ++e) {
        unsigned u = (unsigned)packed[e];
        unsigned hv = hin[(size_t)(u & 0xFFFFFu) * 64 + lane];
        edge(u, hv);
    }
    // body: 8 edges/iter, edge words via 2x uint4, 8 gathers in flight
    for (; e + 8 <= end; e += 8) {
        uint4 p0 = *(const uint4*)(packed + e);
        uint4 p1 = *(const uint4*)(packed + e + 4);
        unsigned h0 = hin[(size_t)(p0.x & 0xFFFFFu) * 64 + lane];
        unsigned h1 = hin[(size_t)(p0.y & 0xFFFFFu) * 64 + lane];
        unsigned h2 = hin[(size_t)(p0.z & 0xFFFFFu) * 64 + lane];
        unsigned h3 = hin[(size_t)(p0.w & 0xFFFFFu) * 64 + lane];
        unsigned h4 = hin[(size_t)(p1.x & 0xFFFFFu) * 64 + lane];
        unsigned h5 = hin[(size_t)(p1.y & 0xFFFFFu) * 64 + lane];
        unsigned h6 = hin[(size_t)(p1.z & 0xFFFFFu) * 64 + lane];
        unsigned h7 = hin[(size_t)(p1.w & 0xFFFFFu) * 64 + lane];
        edge(p0.x, h0); edge(p0.y, h1); edge(p0.z, h2); edge(p0.w, h3);
        edge(p1.x, h4); edge(p1.y, h5); edge(p1.z, h6); edge(p1.w, h7);
    }
    // 4-edge tail
    for (; e + 4 <= end; e += 4) {
        uint4 p0 = *(const uint4*)(packed + e);
        unsigned h0 = hin[(size_t)(p0.x & 0xFFFFFu) * 64 + lane];
        unsigned h1 = hin[(size_t)(p0.y & 0xFFFFFu) * 64 + lane];
        unsigned h2 = hin[(size_t)(p0.z & 0xFFFFFu) * 64 + lane];
        unsigned h3 = hin[(size_t)(p0.w & 0xFFFFFu) * 64 + lane];
        edge(p0.x, h0); edge(p0.y, h1); edge(p0.z, h2); edge(p0.w, h3);
    }
    for (; e < end; ++e) {
        unsigned u = (unsigned)packed[e];
        unsigned hv = hin[(size_t)(u & 0xFFFFFu) * 64 + lane];
        edge(u, hv);
    }
    size_t tb = (size_t)nl * 256 + lane;
    __builtin_nontemporal_store(pack2(a0x, a0y), &tbuf[tb + 0]);
    __builtin_nontemporal_store(pack2(a1x, a1y), &tbuf[tb + 64]);
    __builtin_nontemporal_store(pack2(a2x, a2y), &tbuf[tb + 128]);
    __builtin_nontemporal_store(pack2(a3x, a3y), &tbuf[tb + 192]);
}

// ---------------- conv GEMM (MFMA + global_load_lds, round-7/8 proven) ----------------

__global__ __launch_bounds__(256) void conv_gemm(const unsigned* __restrict__ tbuf, // [len][256]
                                                 const unsigned* __restrict__ hin,  // [N][64]
                                                 const unsigned short* __restrict__ BT, // [128][640]
                                                 const float* __restrict__ hbias,   // [128]
                                                 unsigned* __restrict__ hout,       // [N][64]
                                                 int chunk_start, int chunk_len) {
    __shared__ __align__(16) char As[2][16384];
    __shared__ __align__(16) char Bs[2][16384];
    int tid = threadIdx.x;
    int lane = tid & 63;
    int wave = tid >> 6;
    int wm = wave >> 1, wn = wave & 1;
    int m0 = blockIdx.x * 128;

    auto stage = [&](int c, int buf) {
#pragma unroll
        for (int q = 0; q < 4; ++q) {
            int row = q * 32 + wave * 8 + (lane >> 3);     // row&7 == lane>>3
            int s_src = (lane & 7) ^ (lane >> 3);          // pre-swizzled source slot
            int lr = m0 + row;
            lr = (lr < chunk_len) ? lr : (chunk_len - 1);
            const char* ga = (c < 8)
                ? (const char*)(tbuf + (size_t)lr * 256) + c * 128 + s_src * 16
                : (const char*)(hin + (size_t)(chunk_start + lr) * 64) + (c - 8) * 128 + s_src * 16;
            async16(ga, &As[buf][q * 4096 + wave * 1024]);
            const char* gb = (const char*)BT + (size_t)row * 1280 + c * 128 + s_src * 16;
            async16(gb, &Bs[buf][q * 4096 + wave * 1024]);
        }
    };

    f32x4 acc[4][4];
#pragma unroll
    for (int m = 0; m < 4; ++m)
#pragma unroll
        for (int n = 0; n < 4; ++n) acc[m][n] = (f32x4)0.f;

    stage(0, 0);
    __syncthreads();
    int swz = (lane & 7) << 4;

    for (int c = 0; c < 10; ++c) {
        int buf = c & 1;
        if (c < 9) stage(c + 1, buf ^ 1);
#pragma unroll
        for (int ks = 0; ks < 2; ++ks) {
            short8 a[4], b[4];
            int kb = ks * 64 + (lane >> 4) * 16;
#pragma unroll
            for (int m = 0; m < 4; ++m) {
                int row = wm * 64 + m * 16 + (lane & 15);
                a[m] = *(const short8*)(As[buf] + row * 128 + (kb ^ swz));
            }
#pragma unroll
            for (int n = 0; n < 4; ++n) {
                int col = wn * 64 + n * 16 + (lane & 15);
                b[n] = *(const short8*)(Bs[buf] + col * 128 + (kb ^ swz));
            }
#pragma unroll
            for (int m = 0; m < 4; ++m)
#pragma unroll
                for (int n = 0; n < 4; ++n)
                    acc[m][n] = __builtin_amdgcn_mfma_f32_16x16x32_bf16(a[m], b[n], acc[m][n], 0, 0, 0);
        }
        __syncthreads();
    }

    // epilogue: acc -> LDS -> full-line coalesced stores
    unsigned* olds = (unsigned*)&As[0][0];   // [128 rows][64 dwords] = 32 KB
    int colbase = wn * 64 + (lane & 15);
    float bias_v[4];
#pragma unroll
    for (int n = 0; n < 4; ++n) bias_v[n] = hbias[colbase + n * 16];
#pragma unroll
    for (int m = 0; m < 4; ++m) {
        int rbase = wm * 64 + m * 16 + ((lane >> 4) << 2);
#pragma unroll
        for (int n = 0; n < 4; ++n) {
#pragma unroll
            for (int q = 0; q < 4; ++q) {
                float v = fmaxf(acc[m][n][q] + bias_v[n], 0.f);
                float vo = __shfl_xor(v, 1);
                if ((lane & 1) == 0) {
                    olds[(rbase + q) * 64 + wn * 32 + n * 8 + ((lane & 15) >> 1)] = pack2(v, vo);
                }
            }
        }
    }
    __syncthreads();
#pragma unroll
    for (int i = 0; i < 8; ++i) {
        int j = i * 256 + tid;            // uint4 index over [128][16]
        int row = j >> 4, s = j & 15;
        int gr = m0 + row;
        if (gr < chunk_len) {
            ((uint4*)(hout + (size_t)(chunk_start + gr) * 64))[s] = ((const uint4*)olds)[j];
        }
    }
}

// ---------------- launch ----------------

static inline size_t align256(size_t x) { return (x + 255) & ~(size_t)255; }

extern "C" void kernel_launch(void* const* d_in, const int* in_sizes, int n_in,
                              void* d_out, int out_size, void* d_ws, size_t ws_size,
                              hipStream_t stream) {
    const float* feat   = (const float*)d_in[0];
    const float* win    = (const float*)d_in[1];
    const float* bin_   = (const float*)d_in[2];
    const float* basis0 = (const float*)d_in[3];
    const float* wcomp0 = (const float*)d_in[4];
    const float* loop0  = (const float*)d_in[5];
    const float* hbias0 = (const float*)d_in[6];
    const float* basis1 = (const float*)d_in[7];
    const float* wcomp1 = (const float*)d_in[8];
    const float* loop1  = (const float*)d_in[9];
    const float* hbias1 = (const float*)d_in[10];
    const float* wout   = (const float*)d_in[11];
    const float* bout   = (const float*)d_in[12];
    const int*   src    = (const int*)d_in[13];
    const int*   dst    = (const int*)d_in[14];
    const int*   etyp   = (const int*)d_in[15];
    float* outp = (float*)d_out;

    size_t off = 0;
    char* wsb = (char*)d_ws;
    auto walloc = [&](size_t bytes) { void* p = wsb + off; off += align256(bytes); return p; };
    unsigned* hA  = (unsigned*)walloc((size_t)NN * 64 * 4);     // 25.6 MB
    unsigned* hB  = (unsigned*)walloc((size_t)NN * 64 * 4);     // 25.6 MB
    int* offsets  = (int*)walloc((size_t)(NN + 1) * 4);
    int* counts   = (int*)walloc((size_t)NN * 4);
    int* totals   = (int*)walloc((size_t)NBLK * 4);
    int* gcursor  = (int*)walloc((size_t)NBUK * 4);
    int* packed   = (int*)walloc((size_t)EE * 4);               // 6.4 MB
    unsigned* tmp = (unsigned*)walloc((size_t)EE * 4);          // 6.4 MB
    unsigned short* BT0 = (unsigned short*)walloc((size_t)128 * 640 * 2);
    unsigned short* BT1 = (unsigned short*)walloc((size_t)128 * 640 * 2);
    unsigned short* winT = (unsigned short*)walloc((size_t)128 * 128 * 2);
    unsigned short* woutT = (unsigned short*)walloc((size_t)64 * 128 * 2);
    size_t fixed = off;

    int nchunk = 1;
    while (nchunk < 32) {
        size_t rows = (size_t)(NN + nchunk - 1) / nchunk;
        if (fixed + rows * 1024 <= ws_size) break;
        nchunk *= 2;
    }
    int chunk_rows = (NN + nchunk - 1) / nchunk;
    unsigned* tbuf = (unsigned*)(wsb + fixed);

    // CSR build
    hipMemsetAsync(counts, 0, (size_t)NN * 4, stream);
    count_kernel<<<(EE + 255) / 256, 256, 0, stream>>>(dst, counts);
    scan1<<<NBLK, 256, 0, stream>>>(counts, offsets, totals);
    scan2<<<1, 128, 0, stream>>>(totals, offsets, gcursor);
    scan3<<<(NN + 255) / 256, 256, 0, stream>>>(offsets, totals);
    bin_pass1<<<P1BLOCKS, 256, 0, stream>>>(src, dst, etyp, gcursor, tmp);
    bin_pass2<<<NBUK, 1024, 0, stream>>>(tmp, offsets, packed);

    // weight conversions
    convert_weights<<<(188416 + 255) / 256, 256, 0, stream>>>(
        basis0, loop0, basis1, loop1, win, wout, BT0, BT1, winT, woutT);

    int gblocks = (NN + 127) / 128;  // 782
    // input layer (MFMA, f32 A converted in staging)
    gemm128<128, false, true><<<gblocks, 256, 0, stream>>>(feat, winT, bin_, hA, NN);

    // conv layer 0: hA -> hB
    for (int s = 0; s < NN; s += chunk_rows) {
        int len = (NN - s < chunk_rows) ? (NN - s) : chunk_rows;
        agg_kernel<<<(len + 3) / 4, 256, 0, stream>>>(hA, offsets, packed, wcomp0, tbuf, s, len);
        conv_gemm<<<(len + 127) / 128, 256, 0, stream>>>(tbuf, hA, BT0, hbias0, hB, s, len);
    }
    // conv layer 1: hB -> hA
    for (int s = 0; s < NN; s += chunk_rows) {
        int len = (NN - s < chunk_rows) ? (NN - s) : chunk_rows;
        agg_kernel<<<(len + 3) / 4, 256, 0, stream>>>(hB, offsets, packed, wcomp1, tbuf, s, len);
        conv_gemm<<<(len + 127) / 128, 256, 0, stream>>>(tbuf, hB, BT1, hbias1, hA, s, len);
    }
    // output layer (MFMA): f32 out
    gemm128<64, true, false><<<gblocks, 256, 0, stream>>>(hA, woutT, bout, outp, NN);
}

// Round 10
// 417.455 us; speedup vs baseline: 1.0630x; 1.0630x over previous
//
#include <hip/hip_runtime.h>

#define NN   100000
#define EE   1600000
constexpr int RR = 8;
constexpr int BBASES = 4;
constexpr int SCAN_CHUNK = 1024;
constexpr int NBLK = (NN + SCAN_CHUNK - 1) / SCAN_CHUNK; // 98
constexpr int NBUK = 98;                                 // coarse buckets (dst>>10)
constexpr int EPB  = 4096;                               // edges per bin_pass1 block
constexpr int P1BLOCKS = (EE + EPB - 1) / EPB;           // 391

typedef __attribute__((ext_vector_type(8))) short short8;
typedef __attribute__((ext_vector_type(4))) float f32x4;

__device__ __forceinline__ unsigned pack2(float x, float y) {
    unsigned xu = __float_as_uint(x);
    unsigned yu = __float_as_uint(y);
    xu = (xu + 0x7fffu + ((xu >> 16) & 1u)) >> 16;
    yu = (yu + 0x7fffu + ((yu >> 16) & 1u)) & 0xffff0000u;
    return xu | yu;
}

__device__ __forceinline__ unsigned short bf16r(float x) {
    unsigned u = __float_as_uint(x);
    return (unsigned short)((u + 0x7fffu + ((u >> 16) & 1u)) >> 16);
}

// async global->LDS 16B: per-lane global src, wave-uniform LDS base (+lane*16 by HW)
__device__ __forceinline__ void async16(const void* g, void* l) {
    __builtin_amdgcn_global_load_lds(
        (const __attribute__((address_space(1))) void*)g,
        (__attribute__((address_space(3))) void*)l, 16, 0, 0);
}

// ---------------- CSR build: count + scan ----------------

__global__ __launch_bounds__(256) void count_kernel(const int* __restrict__ dst,
                                                    int* __restrict__ counts) {
    int e = blockIdx.x * 256 + threadIdx.x;
    if (e < EE) atomicAdd(&counts[dst[e]], 1);
}

__global__ __launch_bounds__(256) void scan1(const int* __restrict__ counts,
                                             int* __restrict__ offsets,
                                             int* __restrict__ totals) {
    __shared__ int lds[256];
    int b = blockIdx.x, tid = threadIdx.x;
    int base = b * SCAN_CHUNK + tid * 4;
    int v0 = (base + 0 < NN) ? counts[base + 0] : 0;
    int v1 = (base + 1 < NN) ? counts[base + 1] : 0;
    int v2 = (base + 2 < NN) ? counts[base + 2] : 0;
    int v3 = (base + 3 < NN) ? counts[base + 3] : 0;
    int s0 = v0, s1 = s0 + v1, s2 = s1 + v2, s3 = s2 + v3;
    lds[tid] = s3;
    __syncthreads();
    for (int d = 1; d < 256; d <<= 1) {
        int x = (tid >= d) ? lds[tid - d] : 0;
        __syncthreads();
        lds[tid] += x;
        __syncthreads();
    }
    int incl = lds[tid];
    int prefix = incl - s3;
    if (base + 0 < NN) offsets[base + 0] = prefix;
    if (base + 1 < NN) offsets[base + 1] = prefix + s0;
    if (base + 2 < NN) offsets[base + 2] = prefix + s1;
    if (base + 3 < NN) offsets[base + 3] = prefix + s2;
    if (tid == 255) totals[b] = lds[255];
}

// parallel chunk-total scan (128 thr) + gcursor init
__global__ __launch_bounds__(128) void scan2(int* __restrict__ totals,
                                             int* __restrict__ offsets,
                                             int* __restrict__ gcursor) {
    __shared__ int s[128];
    int tid = threadIdx.x;
    int v = (tid < NBLK) ? totals[tid] : 0;
    s[tid] = v;
    __syncthreads();
    for (int d = 1; d < 128; d <<= 1) {
        int x = (tid >= d) ? s[tid - d] : 0;
        __syncthreads();
        s[tid] += x;
        __syncthreads();
    }
    int excl = s[tid] - v;
    if (tid < NBLK) {
        totals[tid] = excl;
        gcursor[tid] = excl;
    }
    if (tid == NBLK - 1) offsets[NN] = excl + v;   // == EE
}

__global__ __launch_bounds__(256) void scan3(int* __restrict__ offsets,
                                             const int* __restrict__ totals) {
    int i = blockIdx.x * 256 + threadIdx.x;
    if (i < NN) offsets[i] += totals[i >> 10];
}

// ---------------- edge binning ----------------

__global__ __launch_bounds__(256) void bin_pass1(const int* __restrict__ src,
                                                 const int* __restrict__ dst,
                                                 const int* __restrict__ et,
                                                 int* __restrict__ gcursor,
                                                 unsigned* __restrict__ tmp) {
    __shared__ unsigned stage[EPB];   // 16 KB
    __shared__ int hist[128];
    __shared__ int sc[128];
    __shared__ int lb[128];
    __shared__ int gb[128];
    int tid = threadIdx.x;
    long e0 = (long)blockIdx.x * EPB;
    if (tid < 128) hist[tid] = 0;
    __syncthreads();

    unsigned w[16];
    int bk[16], pos[16];
#pragma unroll
    for (int i = 0; i < 16; ++i) {
        long e = e0 + i * 256 + tid;
        bool valid = e < EE;
        int d = valid ? dst[e] : 0;
        int s = valid ? src[e] : 0;
        int r = valid ? et[e] : 0;
        bk[i] = d >> 10;
        w[i] = (unsigned)s | ((unsigned)r << 17) | ((unsigned)(d & 1023) << 20);
        pos[i] = valid ? atomicAdd(&hist[bk[i]], 1) : -1;
    }
    __syncthreads();
    if (tid < 128) sc[tid] = hist[tid];
    __syncthreads();
    for (int d = 1; d < 128; d <<= 1) {
        int v = 0;
        if (tid < 128 && tid >= d) v = sc[tid - d];
        __syncthreads();
        if (tid < 128) sc[tid] += v;
        __syncthreads();
    }
    if (tid < 128) lb[tid] = sc[tid] - hist[tid];
    if (tid < NBUK && hist[tid] > 0) gb[tid] = atomicAdd(&gcursor[tid], hist[tid]);
    __syncthreads();
    int total = sc[127];
#pragma unroll
    for (int i = 0; i < 16; ++i) {
        if (pos[i] >= 0) stage[lb[bk[i]] + pos[i]] = w[i];
    }
    __syncthreads();
    for (int s = tid; s < total; s += 256) {
        int lo = 0, hi = 127;
#pragma unroll
        for (int it = 0; it < 7; ++it) {
            int mid = (lo + hi + 1) >> 1;
            if (lb[mid] <= s) lo = mid; else hi = mid - 1;
        }
        tmp[gb[lo] + (s - lb[lo])] = stage[s];
    }
}

__global__ __launch_bounds__(1024) void bin_pass2(const unsigned* __restrict__ tmp,
                                                  const int* __restrict__ offsets,
                                                  int* __restrict__ packed) {
    __shared__ int cur[1024];
    __shared__ int offs[1025];
    int b = blockIdx.x, tid = threadIdx.x;
    int nb0 = b << 10;
    int nend = nb0 + 1024; if (nend > NN) nend = NN;
    int nloc = nend - nb0;
    cur[tid] = 0;
    for (int i = tid; i <= nloc; i += 1024) offs[i] = offsets[nb0 + i];
    __syncthreads();
    int beg = offs[0], end = offs[nloc];
    for (int e = beg + tid; e < end; e += 1024) {
        unsigned wv = tmp[e];
        int dl = (wv >> 20) & 1023;
        int p = offs[dl] + atomicAdd(&cur[dl], 1);
        packed[p] = (int)((wv & 0x1FFFFu) | (((wv >> 17) & 7u) << 20));
    }
}

// ---------------- weight conversions ----------------

__global__ __launch_bounds__(256) void convert_weights(const float* __restrict__ basis0,
                                                       const float* __restrict__ loop0,
                                                       const float* __restrict__ basis1,
                                                       const float* __restrict__ loop1,
                                                       const float* __restrict__ win,
                                                       const float* __restrict__ wout,
                                                       unsigned short* __restrict__ BT0,
                                                       unsigned short* __restrict__ BT1,
                                                       unsigned short* __restrict__ winT,
                                                       unsigned short* __restrict__ woutT) {
    int i = blockIdx.x * 256 + threadIdx.x;
    if (i < 81920) {
        int n = i / 640, k = i % 640;
        BT0[i] = bf16r(k < 512 ? basis0[(size_t)k * 128 + n] : loop0[(size_t)(k - 512) * 128 + n]);
    } else if (i < 163840) {
        int j = i - 81920;
        int n = j / 640, k = j % 640;
        BT1[j] = bf16r(k < 512 ? basis1[(size_t)k * 128 + n] : loop1[(size_t)(k - 512) * 128 + n]);
    } else if (i < 180224) {
        int j = i - 163840;
        int n = j >> 7, k = j & 127;
        winT[j] = bf16r(win[(size_t)k * 128 + n]);
    } else if (i < 188416) {
        int j = i - 180224;
        int n = j >> 7, k = j & 127;
        woutT[j] = bf16r(wout[(size_t)k * 64 + n]);
    }
}

// ---------------- MFMA GEMM, K=128 (input layer) ----------------
template <int NC, bool F32OUT, bool AF32>
__global__ __launch_bounds__(256) void gemm128(const void* __restrict__ Aptr,
                                               const unsigned short* __restrict__ BT,
                                               const float* __restrict__ bias,
                                               void* __restrict__ outp, int M) {
    constexpr int NFRAG = NC / 32;
    constexpr int BQ = NC * 8 / 256;
    __shared__ __align__(16) char As[2][16384];
    __shared__ __align__(16) char Bs[2][NC * 128];
    int tid = threadIdx.x;
    int lane = tid & 63;
    int wave = tid >> 6;
    int wm = wave >> 1, wn = wave & 1;
    int m0 = blockIdx.x * 128;

    uint4 areg[4], breg[BQ];
    auto loadA = [&](int c) {
#pragma unroll
        for (int q = 0; q < 4; ++q) {
            int lin = q * 256 + tid;
            int row = lin >> 3, slot = lin & 7;
            int gr = m0 + row;
            gr = (gr < M) ? gr : (M - 1);
            if (AF32) {
                const float* fp = (const float*)Aptr + (size_t)gr * 128 + c * 64 + slot * 8;
                float4 v0 = *(const float4*)fp;
                float4 v1 = *(const float4*)(fp + 4);
                areg[q].x = pack2(v0.x, v0.y);
                areg[q].y = pack2(v0.z, v0.w);
                areg[q].z = pack2(v1.x, v1.y);
                areg[q].w = pack2(v1.z, v1.w);
            } else {
                areg[q] = *(const uint4*)((const char*)Aptr + (size_t)gr * 256 + c * 128 + slot * 16);
            }
        }
    };
    auto loadB = [&](int c) {
#pragma unroll
        for (int q = 0; q < BQ; ++q) {
            int lin = q * 256 + tid;
            int n = lin >> 3, slot = lin & 7;
            breg[q] = *(const uint4*)((const char*)BT + (size_t)n * 256 + c * 128 + slot * 16);
        }
    };

    f32x4 acc[4][NFRAG];
#pragma unroll
    for (int m = 0; m < 4; ++m)
#pragma unroll
        for (int n = 0; n < NFRAG; ++n) acc[m][n] = (f32x4)0.f;

    loadA(0); loadB(0);
    int swz = (lane & 7) << 4;

    for (int c = 0; c < 2; ++c) {
        int buf = c & 1;
#pragma unroll
        for (int q = 0; q < 4; ++q) {
            int lin = q * 256 + tid;
            int row = lin >> 3, slot = lin & 7;
            *(uint4*)(As[buf] + row * 128 + ((slot * 16) ^ ((row & 7) << 4))) = areg[q];
        }
#pragma unroll
        for (int q = 0; q < BQ; ++q) {
            int lin = q * 256 + tid;
            int row = lin >> 3, slot = lin & 7;
            *(uint4*)(Bs[buf] + row * 128 + ((slot * 16) ^ ((row & 7) << 4))) = breg[q];
        }
        __syncthreads();
        if (c < 1) { loadA(1); loadB(1); }
#pragma unroll
        for (int ks = 0; ks < 2; ++ks) {
            short8 a[4], b[NFRAG];
            int kb = ks * 64 + (lane >> 4) * 16;
#pragma unroll
            for (int m = 0; m < 4; ++m) {
                int row = wm * 64 + m * 16 + (lane & 15);
                a[m] = *(const short8*)(As[buf] + row * 128 + (kb ^ swz));
            }
#pragma unroll
            for (int n = 0; n < NFRAG; ++n) {
                int col = wn * (NC / 2) + n * 16 + (lane & 15);
                b[n] = *(const short8*)(Bs[buf] + col * 128 + (kb ^ swz));
            }
#pragma unroll
            for (int m = 0; m < 4; ++m)
#pragma unroll
                for (int n = 0; n < NFRAG; ++n)
                    acc[m][n] = __builtin_amdgcn_mfma_f32_16x16x32_bf16(a[m], b[n], acc[m][n], 0, 0, 0);
        }
        __syncthreads();
    }

    int colbase = wn * (NC / 2) + (lane & 15);
    float bias_v[NFRAG];
#pragma unroll
    for (int n = 0; n < NFRAG; ++n) bias_v[n] = bias[colbase + n * 16];
#pragma unroll
    for (int m = 0; m < 4; ++m) {
        int rl0 = m0 + wm * 64 + m * 16 + ((lane >> 4) << 2);
#pragma unroll
        for (int n = 0; n < NFRAG; ++n) {
            int col = colbase + n * 16;
#pragma unroll
            for (int q = 0; q < 4; ++q) {
                float v = fmaxf(acc[m][n][q] + bias_v[n], 0.f);
                int row = rl0 + q;
                if (F32OUT) {
                    if (row < M) ((float*)outp)[(size_t)row * NC + col] = v;
                } else {
                    float vo = __shfl_xor(v, 1);
                    if (((lane & 1) == 0) && row < M)
                        ((unsigned*)outp)[(size_t)row * (NC / 2) + (col >> 1)] = pack2(v, vo);
                }
            }
        }
    }
}

// ---------------- aggregation (round-8/9 body) ----------------

__global__ __launch_bounds__(256) void agg_kernel(const unsigned* __restrict__ hin, // [N][64] bf16x2
                                                  const int* __restrict__ offsets,
                                                  const int* __restrict__ packed,
                                                  const float* __restrict__ wcomp,  // [8][4]
                                                  unsigned* __restrict__ tbuf,      // [len][256]
                                                  int chunk_start, int chunk_len) {
    __shared__ float wc[32];
    int tid = threadIdx.x;
    if (tid < 32) wc[tid] = wcomp[tid];
    __syncthreads();
    int nl = blockIdx.x * 4 + (tid >> 6);
    int lane = tid & 63;
    if (nl >= chunk_len) return;
    int n = chunk_start + nl;
    int beg = offsets[n], end = offsets[n + 1];
    float a0x = 0.f, a0y = 0.f, a1x = 0.f, a1y = 0.f;
    float a2x = 0.f, a2y = 0.f, a3x = 0.f, a3y = 0.f;
    auto edge = [&](unsigned u, unsigned hv) {
        int r = (int)(u >> 20);
        float hx = __uint_as_float(hv << 16);
        float hy = __uint_as_float(hv & 0xffff0000u);
        float w0 = wc[r * 4 + 0], w1 = wc[r * 4 + 1];
        float w2 = wc[r * 4 + 2], w3 = wc[r * 4 + 3];
        a0x = fmaf(w0, hx, a0x); a0y = fmaf(w0, hy, a0y);
        a1x = fmaf(w1, hx, a1x); a1y = fmaf(w1, hy, a1y);
        a2x = fmaf(w2, hx, a2x); a2y = fmaf(w2, hy, a2y);
        a3x = fmaf(w3, hx, a3x); a3y = fmaf(w3, hy, a3y);
    };
    int e = beg;
    int ehead = (beg + 3) & ~3;
    if (ehead > end) ehead = end;
    for (; e < ehead; ++e) {
        unsigned u = (unsigned)packed[e];
        unsigned hv = hin[(size_t)(u & 0xFFFFFu) * 64 + lane];
        edge(u, hv);
    }
    for (; e + 8 <= end; e += 8) {
        uint4 p0 = *(const uint4*)(packed + e);
        uint4 p1 = *(const uint4*)(packed + e + 4);
        unsigned h0 = hin[(size_t)(p0.x & 0xFFFFFu) * 64 + lane];
        unsigned h1 = hin[(size_t)(p0.y & 0xFFFFFu) * 64 + lane];
        unsigned h2 = hin[(size_t)(p0.z & 0xFFFFFu) * 64 + lane];
        unsigned h3 = hin[(size_t)(p0.w & 0xFFFFFu) * 64 + lane];
        unsigned h4 = hin[(size_t)(p1.x & 0xFFFFFu) * 64 + lane];
        unsigned h5 = hin[(size_t)(p1.y & 0xFFFFFu) * 64 + lane];
        unsigned h6 = hin[(size_t)(p1.z & 0xFFFFFu) * 64 + lane];
        unsigned h7 = hin[(size_t)(p1.w & 0xFFFFFu) * 64 + lane];
        edge(p0.x, h0); edge(p0.y, h1); edge(p0.z, h2); edge(p0.w, h3);
        edge(p1.x, h4); edge(p1.y, h5); edge(p1.z, h6); edge(p1.w, h7);
    }
    for (; e + 4 <= end; e += 4) {
        uint4 p0 = *(const uint4*)(packed + e);
        unsigned h0 = hin[(size_t)(p0.x & 0xFFFFFu) * 64 + lane];
        unsigned h1 = hin[(size_t)(p0.y & 0xFFFFFu) * 64 + lane];
        unsigned h2 = hin[(size_t)(p0.z & 0xFFFFFu) * 64 + lane];
        unsigned h3 = hin[(size_t)(p0.w & 0xFFFFFu) * 64 + lane];
        edge(p0.x, h0); edge(p0.y, h1); edge(p0.z, h2); edge(p0.w, h3);
    }
    for (; e < end; ++e) {
        unsigned u = (unsigned)packed[e];
        unsigned hv = hin[(size_t)(u & 0xFFFFFu) * 64 + lane];
        edge(u, hv);
    }
    size_t tb = (size_t)nl * 256 + lane;
    __builtin_nontemporal_store(pack2(a0x, a0y), &tbuf[tb + 0]);
    __builtin_nontemporal_store(pack2(a1x, a1y), &tbuf[tb + 64]);
    __builtin_nontemporal_store(pack2(a2x, a2y), &tbuf[tb + 128]);
    __builtin_nontemporal_store(pack2(a3x, a3y), &tbuf[tb + 192]);
}

// ---------------- conv GEMM (+ optional fused output layer) ----------------
// FUSE_OUT=false: hout = relu([t|h] @ BT^T + hbias) -> bf16.
// FUSE_OUT=true : h1 = relu(...) kept in LDS (swizzled), then
//                 outp = relu(h1 @ WoutT^T + bout) -> f32. hout not written.

template <bool FUSE_OUT>
__global__ __launch_bounds__(256) void conv_gemm(const unsigned* __restrict__ tbuf, // [len][256]
                                                 const unsigned* __restrict__ hin,  // [N][64]
                                                 const unsigned short* __restrict__ BT, // [128][640]
                                                 const float* __restrict__ hbias,   // [128]
                                                 unsigned* __restrict__ hout,       // [N][64]
                                                 const unsigned short* __restrict__ WoutT, // [64][128]
                                                 const float* __restrict__ bout,    // [64]
                                                 float* __restrict__ outp,          // [N][64]
                                                 int chunk_start, int chunk_len) {
    __shared__ __align__(16) char As[2][16384];
    __shared__ __align__(16) char Bs[2][16384];
    __shared__ __align__(16) char Ws[16384];   // woutT tile (FUSE_OUT only)
    int tid = threadIdx.x;
    int lane = tid & 63;
    int wave = tid >> 6;
    int wm = wave >> 1, wn = wave & 1;
    int m0 = blockIdx.x * 128;

    auto stage = [&](int c, int buf) {
#pragma unroll
        for (int q = 0; q < 4; ++q) {
            int row = q * 32 + wave * 8 + (lane >> 3);     // row&7 == lane>>3
            int s_src = (lane & 7) ^ (lane >> 3);          // pre-swizzled source slot
            int lr = m0 + row;
            lr = (lr < chunk_len) ? lr : (chunk_len - 1);
            const char* ga = (c < 8)
                ? (const char*)(tbuf + (size_t)lr * 256) + c * 128 + s_src * 16
                : (const char*)(hin + (size_t)(chunk_start + lr) * 64) + (c - 8) * 128 + s_src * 16;
            async16(ga, &As[buf][q * 4096 + wave * 1024]);
            const char* gb = (const char*)BT + (size_t)row * 1280 + c * 128 + s_src * 16;
            async16(gb, &Bs[buf][q * 4096 + wave * 1024]);
        }
    };

    f32x4 acc[4][4];
#pragma unroll
    for (int m = 0; m < 4; ++m)
#pragma unroll
        for (int n = 0; n < 4; ++n) acc[m][n] = (f32x4)0.f;

    stage(0, 0);
    if (FUSE_OUT) {
        // stage woutT [64][256B] into Ws with pre-swizzled source slot
#pragma unroll
        for (int q = 0; q < 4; ++q) {
            int row = q * 16 + wave * 4 + (lane >> 4);     // 0..63
            int s_src = (lane & 15) ^ (row & 7);
            async16((const char*)WoutT + (size_t)row * 256 + s_src * 16,
                    &Ws[q * 4096 + wave * 1024]);
        }
    }
    __syncthreads();
    int swz = (lane & 7) << 4;

    for (int c = 0; c < 10; ++c) {
        int buf = c & 1;
        if (c < 9) stage(c + 1, buf ^ 1);
#pragma unroll
        for (int ks = 0; ks < 2; ++ks) {
            short8 a[4], b[4];
            int kb = ks * 64 + (lane >> 4) * 16;
#pragma unroll
            for (int m = 0; m < 4; ++m) {
                int row = wm * 64 + m * 16 + (lane & 15);
                a[m] = *(const short8*)(As[buf] + row * 128 + (kb ^ swz));
            }
#pragma unroll
            for (int n = 0; n < 4; ++n) {
                int col = wn * 64 + n * 16 + (lane & 15);
                b[n] = *(const short8*)(Bs[buf] + col * 128 + (kb ^ swz));
            }
#pragma unroll
            for (int m = 0; m < 4; ++m)
#pragma unroll
                for (int n = 0; n < 4; ++n)
                    acc[m][n] = __builtin_amdgcn_mfma_f32_16x16x32_bf16(a[m], b[n], acc[m][n], 0, 0, 0);
        }
        __syncthreads();
    }

    unsigned* olds = (unsigned*)&As[0][0];   // [128 rows][64 dwords] = 32 KB
    int colbase = wn * 64 + (lane & 15);
    float bias_v[4];
#pragma unroll
    for (int n = 0; n < 4; ++n) bias_v[n] = hbias[colbase + n * 16];

    if (!FUSE_OUT) {
        // h-out epilogue: acc -> LDS (linear) -> full-line coalesced stores
#pragma unroll
        for (int m = 0; m < 4; ++m) {
            int rbase = wm * 64 + m * 16 + ((lane >> 4) << 2);
#pragma unroll
            for (int n = 0; n < 4; ++n) {
#pragma unroll
                for (int q = 0; q < 4; ++q) {
                    float v = fmaxf(acc[m][n][q] + bias_v[n], 0.f);
                    float vo = __shfl_xor(v, 1);
                    if ((lane & 1) == 0) {
                        olds[(rbase + q) * 64 + wn * 32 + n * 8 + ((lane & 15) >> 1)] = pack2(v, vo);
                    }
                }
            }
        }
        __syncthreads();
#pragma unroll
        for (int i = 0; i < 8; ++i) {
            int j = i * 256 + tid;            // uint4 index over [128][16]
            int row = j >> 4, s = j & 15;
            int gr = m0 + row;
            if (gr < chunk_len) {
                ((uint4*)(hout + (size_t)(chunk_start + gr) * 64))[s] = ((const uint4*)olds)[j];
            }
        }
    } else {
        // write h1 to LDS with XOR swizzle (dword d ^= (row&7)<<2)
#pragma unroll
        for (int m = 0; m < 4; ++m) {
            int rbase = wm * 64 + m * 16 + ((lane >> 4) << 2);
#pragma unroll
            for (int n = 0; n < 4; ++n) {
#pragma unroll
                for (int q = 0; q < 4; ++q) {
                    float v = fmaxf(acc[m][n][q] + bias_v[n], 0.f);
                    float vo = __shfl_xor(v, 1);
                    if ((lane & 1) == 0) {
                        int row = rbase + q;
                        int d = wn * 32 + n * 8 + ((lane & 15) >> 1);
                        olds[row * 64 + (d ^ ((row & 7) << 2))] = pack2(v, vo);
                    }
                }
            }
        }
        __syncthreads();
        // mini-GEMM: out = relu(h1[128x128] @ WoutT^T[64x128] + bout), f32
        f32x4 acc2[4][2];
#pragma unroll
        for (int m = 0; m < 4; ++m)
#pragma unroll
            for (int n = 0; n < 2; ++n) acc2[m][n] = (f32x4)0.f;
#pragma unroll
        for (int ks = 0; ks < 4; ++ks) {
            int kb = ks * 64 + (lane >> 4) * 16;   // byte offset within 256B row
            short8 a2[4], b2[2];
#pragma unroll
            for (int m = 0; m < 4; ++m) {
                int row = wm * 64 + m * 16 + (lane & 15);
                a2[m] = *(const short8*)((const char*)olds + row * 256 + (kb ^ ((row & 7) << 4)));
            }
#pragma unroll
            for (int n = 0; n < 2; ++n) {
                int col = wn * 32 + n * 16 + (lane & 15);
                b2[n] = *(const short8*)(Ws + col * 256 + (kb ^ ((col & 7) << 4)));
            }
#pragma unroll
            for (int m = 0; m < 4; ++m)
#pragma unroll
                for (int n = 0; n < 2; ++n)
                    acc2[m][n] = __builtin_amdgcn_mfma_f32_16x16x32_bf16(a2[m], b2[n], acc2[m][n], 0, 0, 0);
        }
        int colb = wn * 32 + (lane & 15);
        float bv2[2];
#pragma unroll
        for (int n = 0; n < 2; ++n) bv2[n] = bout[colb + n * 16];
#pragma unroll
        for (int m = 0; m < 4; ++m) {
            int rl0 = wm * 64 + m * 16 + ((lane >> 4) << 2);
#pragma unroll
            for (int n = 0; n < 2; ++n) {
#pragma unroll
                for (int q = 0; q < 4; ++q) {
                    int row = rl0 + q;
                    if (m0 + row < chunk_len) {
                        float v = fmaxf(acc2[m][n][q] + bv2[n], 0.f);
                        outp[(size_t)(chunk_start + m0 + row) * 64 + colb + n * 16] = v;
                    }
                }
            }
        }
    }
}

// ---------------- launch ----------------

static inline size_t align256(size_t x) { return (x + 255) & ~(size_t)255; }

extern "C" void kernel_launch(void* const* d_in, const int* in_sizes, int n_in,
                              void* d_out, int out_size, void* d_ws, size_t ws_size,
                              hipStream_t stream) {
    const float* feat   = (const float*)d_in[0];
    const float* win    = (const float*)d_in[1];
    const float* bin_   = (const float*)d_in[2];
    const float* basis0 = (const float*)d_in[3];
    const float* wcomp0 = (const float*)d_in[4];
    const float* loop0  = (const float*)d_in[5];
    const float* hbias0 = (const float*)d_in[6];
    const float* basis1 = (const float*)d_in[7];
    const float* wcomp1 = (const float*)d_in[8];
    const float* loop1  = (const float*)d_in[9];
    const float* hbias1 = (const float*)d_in[10];
    const float* wout   = (const float*)d_in[11];
    const float* bout   = (const float*)d_in[12];
    const int*   src    = (const int*)d_in[13];
    const int*   dst    = (const int*)d_in[14];
    const int*   etyp   = (const int*)d_in[15];
    float* outp = (float*)d_out;

    size_t off = 0;
    char* wsb = (char*)d_ws;
    auto walloc = [&](size_t bytes) { void* p = wsb + off; off += align256(bytes); return p; };
    unsigned* hA  = (unsigned*)walloc((size_t)NN * 64 * 4);     // 25.6 MB
    unsigned* hB  = (unsigned*)walloc((size_t)NN * 64 * 4);     // 25.6 MB
    int* offsets  = (int*)walloc((size_t)(NN + 1) * 4);
    int* counts   = (int*)walloc((size_t)NN * 4);
    int* totals   = (int*)walloc((size_t)NBLK * 4);
    int* gcursor  = (int*)walloc((size_t)NBUK * 4);
    int* packed   = (int*)walloc((size_t)EE * 4);               // 6.4 MB
    unsigned* tmp = (unsigned*)walloc((size_t)EE * 4);          // 6.4 MB
    unsigned short* BT0 = (unsigned short*)walloc((size_t)128 * 640 * 2);
    unsigned short* BT1 = (unsigned short*)walloc((size_t)128 * 640 * 2);
    unsigned short* winT = (unsigned short*)walloc((size_t)128 * 128 * 2);
    unsigned short* woutT = (unsigned short*)walloc((size_t)64 * 128 * 2);
    size_t fixed = off;

    int nchunk = 1;
    while (nchunk < 32) {
        size_t rows = (size_t)(NN + nchunk - 1) / nchunk;
        if (fixed + rows * 1024 <= ws_size) break;
        nchunk *= 2;
    }
    int chunk_rows = (NN + nchunk - 1) / nchunk;
    unsigned* tbuf = (unsigned*)(wsb + fixed);

    // CSR build
    hipMemsetAsync(counts, 0, (size_t)NN * 4, stream);
    count_kernel<<<(EE + 255) / 256, 256, 0, stream>>>(dst, counts);
    scan1<<<NBLK, 256, 0, stream>>>(counts, offsets, totals);
    scan2<<<1, 128, 0, stream>>>(totals, offsets, gcursor);
    scan3<<<(NN + 255) / 256, 256, 0, stream>>>(offsets, totals);
    bin_pass1<<<P1BLOCKS, 256, 0, stream>>>(src, dst, etyp, gcursor, tmp);
    bin_pass2<<<NBUK, 1024, 0, stream>>>(tmp, offsets, packed);

    // weight conversions
    convert_weights<<<(188416 + 255) / 256, 256, 0, stream>>>(
        basis0, loop0, basis1, loop1, win, wout, BT0, BT1, winT, woutT);

    int gblocks = (NN + 127) / 128;  // 782
    // input layer (MFMA, f32 A converted in staging)
    gemm128<128, false, true><<<gblocks, 256, 0, stream>>>(feat, winT, bin_, hA, NN);

    // conv layer 0: hA -> hB
    for (int s = 0; s < NN; s += chunk_rows) {
        int len = (NN - s < chunk_rows) ? (NN - s) : chunk_rows;
        agg_kernel<<<(len + 3) / 4, 256, 0, stream>>>(hA, offsets, packed, wcomp0, tbuf, s, len);
        conv_gemm<false><<<(len + 127) / 128, 256, 0, stream>>>(
            tbuf, hA, BT0, hbias0, hB, nullptr, nullptr, nullptr, s, len);
    }
    // conv layer 1 + fused output layer: hB -> out
    for (int s = 0; s < NN; s += chunk_rows) {
        int len = (NN - s < chunk_rows) ? (NN - s) : chunk_rows;
        agg_kernel<<<(len + 3) / 4, 256, 0, stream>>>(hB, offsets, packed, wcomp1, tbuf, s, len);
        conv_gemm<true><<<(len + 127) / 128, 256, 0, stream>>>(
            tbuf, hB, BT1, hbias1, nullptr, woutT, bout, outp, s, len);
    }
}